// Round 4
// baseline (45.800 us; speedup 1.0000x reference)
//
#include <hip/hip_runtime.h>

// x: [2,2,8,64,64,64] fp32 0/1 -> 2048 images of 64x64.
// Per image: #4-connected components; per group of 64 images: sum // 64 -> float.
//
// One 64-lane wave per image; lane r owns row r:
//   - loads its row via 16 independent dwordx4 (high MLP, no ballot chains)
//   - builds the row's 64-bit mask with local compares
// Horizontal runs are free (bitmask). Union-find over runs (id = row*32+rank)
// in LDS; components = total_runs - successful_merges (no root scan).
constexpr int NPIX = 64 * 64;
constexpr int PATCHES = 64;
constexpr int RUNS_PER_ROW = 32;
constexpr int TABLE = 64 * RUNS_PER_ROW;  // 2048 slots per image
constexpr int IMGS_PER_BLOCK = 4;         // 4 waves / 256-thread block, 32 KB LDS

// Find with path halving (benign race: only ever points i to an ancestor).
__device__ __forceinline__ int find_root(volatile int* p, int i) {
    while (true) {
        int pi = p[i];
        if (pi == i) return i;
        int gp = p[pi];
        if (gp == pi) return pi;
        p[i] = gp;
        i = gp;
    }
}

// Attach larger root under smaller; parents strictly decrease -> acyclic.
// Returns 1 iff a merge (two distinct trees joined) happened here.
__device__ __forceinline__ int unite(int* p, int a, int b) {
    int ra = find_root(p, a), rb = find_root(p, b);
    while (ra != rb) {
        if (ra < rb) { int t = ra; ra = rb; rb = t; }
        int old = atomicCAS(&p[ra], ra, rb);
        if (old == ra) return 1;
        ra = find_root(p, old);
        rb = find_root(p, rb);
    }
    return 0;
}

__global__ __launch_bounds__(256) void cc_kernel(const float* __restrict__ in,
                                                 int* __restrict__ group_sums) {
    __shared__ int par_all[IMGS_PER_BLOCK][TABLE];  // 32 KB
    const int wid = threadIdx.x >> 6;
    const int lane = threadIdx.x & 63;
    const int img = blockIdx.x * IMGS_PER_BLOCK + wid;
    int* par = par_all[wid];

    // ---- issue all 16 row loads up front (64B-line-covering per lane) ----
    const float4* row =
        reinterpret_cast<const float4*>(in + (size_t)img * NPIX + lane * 64);
    float4 buf[16];
#pragma unroll
    for (int k = 0; k < 16; ++k) buf[k] = row[k];

    // ---- identity-init run table while loads are in flight ----
#pragma unroll
    for (int q = 0; q < TABLE / 256; ++q) {
        int base = q * 256 + lane * 4;
        *reinterpret_cast<int4*>(&par[base]) =
            make_int4(base, base + 1, base + 2, base + 3);
    }
    __syncthreads();  // orders LDS init only; global loads still in flight

    // ---- build this lane's row mask (local compares, 2 VALU/pixel) ----
    unsigned lo = 0, hi = 0;
#pragma unroll
    for (int k = 0; k < 8; ++k) {
        lo |= (buf[k].x > 0.5f ? 1u : 0u) << (4 * k);
        lo |= (buf[k].y > 0.5f ? 2u : 0u) << (4 * k);
        lo |= (buf[k].z > 0.5f ? 4u : 0u) << (4 * k);
        lo |= (buf[k].w > 0.5f ? 8u : 0u) << (4 * k);
    }
#pragma unroll
    for (int k = 0; k < 8; ++k) {
        hi |= (buf[8 + k].x > 0.5f ? 1u : 0u) << (4 * k);
        hi |= (buf[8 + k].y > 0.5f ? 2u : 0u) << (4 * k);
        hi |= (buf[8 + k].z > 0.5f ? 4u : 0u) << (4 * k);
        hi |= (buf[8 + k].w > 0.5f ? 8u : 0u) << (4 * k);
    }
    const unsigned long long m = ((unsigned long long)hi << 32) | lo;

    const unsigned long long s = m & ~(m << 1);  // run-start bits
    const int nrun = __popcll(s);

    // ---- vertical unions: lane r merges rows r, r+1 at overlap starts ----
    int merges = 0;
    unsigned long long mn = __shfl_down(m, 1, 64);
    unsigned long long sn = __shfl_down(s, 1, 64);
    if (lane < 63) {
        unsigned long long both = m & mn;
        unsigned long long ov = both & ~(both << 1);  // one union per segment
        while (ov) {
            int x = __builtin_ctzll(ov);
            ov &= ov - 1;
            unsigned long long below = (2ull << x) - 1;  // bits 0..x
            int ida = lane * RUNS_PER_ROW + __popcll(s & below) - 1;
            int idb = (lane + 1) * RUNS_PER_ROW + __popcll(sn & below) - 1;
            merges += unite(par, ida, idb);
        }
    }

    // ---- components = runs - merges; wave-reduce ----
    int cnt = nrun - merges;
#pragma unroll
    for (int d = 32; d > 0; d >>= 1) cnt += __shfl_xor(cnt, d, 64);
    if (lane == 0) atomicAdd(&group_sums[img / PATCHES], cnt);
}

__global__ void finalize_kernel(const int* __restrict__ group_sums,
                                float* __restrict__ out, int ngroups) {
    int g = threadIdx.x + blockIdx.x * blockDim.x;
    if (g < ngroups) out[g] = (float)(group_sums[g] / PATCHES);
}

extern "C" void kernel_launch(void* const* d_in, const int* in_sizes, int n_in,
                              void* d_out, int out_size, void* d_ws, size_t ws_size,
                              hipStream_t stream) {
    const float* x = (const float*)d_in[0];
    float* out = (float*)d_out;
    int* ws = (int*)d_ws;

    const int nimg = in_sizes[0] / NPIX;  // 2048
    const int ngroups = out_size;         // 32

    hipMemsetAsync(ws, 0, ngroups * sizeof(int), stream);
    cc_kernel<<<nimg / IMGS_PER_BLOCK, 256, 0, stream>>>(x, ws);
    finalize_kernel<<<1, 64, 0, stream>>>(ws, out, ngroups);
}

// Round 5
// 37.766 us; speedup vs baseline: 1.2127x; 1.2127x over previous
//
#include <hip/hip_runtime.h>

// x: [2,2,8,64,64,64] fp32 0/1 -> 2048 images of 64x64.
// Per image: #4-connected components; per group of 64 images: sum // 64 -> float.
//
// One 256-thread block per image; thread = 4*row + quarter. Each thread loads
// 16 consecutive pixels (one 64B line), builds a 16-bit quarter mask; 2x
// shfl_xor(width=4) assemble full row masks in-register. Horizontal runs are
// free (bitmask); union-find over runs (id = row*32+rank) in an 8 KB LDS
// table; each thread unions only overlap segments STARTING in its quarter.
// components = total_runs - successful_merges. 2048 blocks x 4 waves = 8192
// waves -> full occupancy; __launch_bounds__(256,8) keeps VGPR <= 64.
constexpr int NPIX = 64 * 64;
constexpr int PATCHES = 64;
constexpr int RUNS_PER_ROW = 32;
constexpr int TABLE = 64 * RUNS_PER_ROW;  // 2048 run slots

// Find with path halving (benign race: only ever points i to an ancestor).
__device__ __forceinline__ int find_root(volatile int* p, int i) {
    while (true) {
        int pi = p[i];
        if (pi == i) return i;
        int gp = p[pi];
        if (gp == pi) return pi;
        p[i] = gp;
        i = gp;
    }
}

// Attach larger root under smaller; parents strictly decrease -> acyclic.
// Returns 1 iff a merge (two distinct trees joined) happened here.
__device__ __forceinline__ int unite(int* p, int a, int b) {
    int ra = find_root(p, a), rb = find_root(p, b);
    while (ra != rb) {
        if (ra < rb) { int t = ra; ra = rb; rb = t; }
        int old = atomicCAS(&p[ra], ra, rb);
        if (old == ra) return 1;
        ra = find_root(p, old);
        rb = find_root(p, rb);
    }
    return 0;
}

__global__ __launch_bounds__(256, 8) void cc_kernel(const float* __restrict__ in,
                                                    int* __restrict__ group_sums) {
    __shared__ int par[TABLE];               // 8 KB
    __shared__ unsigned long long mrow[64];  // 512 B row masks
    __shared__ int wpart[4];
    const int tid = threadIdx.x;
    const int img = blockIdx.x;
    const int r = tid >> 2;  // row 0..63
    const int q = tid & 3;   // quarter 0..3

    // ---- load 16 consecutive pixels (4 x float4 = one 64B line) ----
    const float4* src =
        reinterpret_cast<const float4*>(in + (size_t)img * NPIX + r * 64 + q * 16);
    float4 buf[4];
#pragma unroll
    for (int k = 0; k < 4; ++k) buf[k] = src[k];

    // ---- identity-init run table while loads are in flight ----
    {
        int b0 = tid * 4;
        *reinterpret_cast<int4*>(&par[b0]) = make_int4(b0, b0 + 1, b0 + 2, b0 + 3);
        int b1 = 1024 + tid * 4;
        *reinterpret_cast<int4*>(&par[b1]) = make_int4(b1, b1 + 1, b1 + 2, b1 + 3);
    }

    // ---- 16-bit quarter mask, then assemble full row mask (width-4 bfly) ----
    unsigned qm = 0;
#pragma unroll
    for (int k = 0; k < 4; ++k) {
        qm |= (buf[k].x > 0.5f ? 1u : 0u) << (4 * k);
        qm |= (buf[k].y > 0.5f ? 2u : 0u) << (4 * k);
        qm |= (buf[k].z > 0.5f ? 4u : 0u) << (4 * k);
        qm |= (buf[k].w > 0.5f ? 8u : 0u) << (4 * k);
    }
    unsigned long long m = (unsigned long long)qm << (16 * q);
    m |= __shfl_xor(m, 1, 4);
    m |= __shfl_xor(m, 2, 4);  // all 4 threads of row r now hold full mask

    if (q == 0) mrow[r] = m;
    __syncthreads();  // par + mrow visible

    const unsigned long long ma = m;
    const unsigned long long mb = (r < 63) ? mrow[r + 1] : 0ull;
    const unsigned long long sa = ma & ~(ma << 1);
    const unsigned long long sb = mb & ~(mb << 1);
    const unsigned long long qmask = 0xFFFFull << (16 * q);

    int cnt = __popcll(sa & qmask);  // quarter-disjoint run-start count

    // ---- unions: overlap segments whose start bit is in this quarter ----
    unsigned long long both = ma & mb;
    unsigned long long ov = (both & ~(both << 1)) & qmask;
    while (ov) {
        int x = __builtin_ctzll(ov);
        ov &= ov - 1;
        unsigned long long below = (2ull << x) - 1;  // bits 0..x
        int ida = r * RUNS_PER_ROW + __popcll(sa & below) - 1;
        int idb = (r + 1) * RUNS_PER_ROW + __popcll(sb & below) - 1;
        cnt -= unite(par, ida, idb);
    }

    // ---- block reduction of (runs - merges) ----
#pragma unroll
    for (int d = 32; d > 0; d >>= 1) cnt += __shfl_xor(cnt, d, 64);
    if ((tid & 63) == 0) wpart[tid >> 6] = cnt;
    __syncthreads();
    if (tid == 0)
        atomicAdd(&group_sums[img / PATCHES],
                  wpart[0] + wpart[1] + wpart[2] + wpart[3]);
}

__global__ void finalize_kernel(const int* __restrict__ group_sums,
                                float* __restrict__ out, int ngroups) {
    int g = threadIdx.x + blockIdx.x * blockDim.x;
    if (g < ngroups) out[g] = (float)(group_sums[g] / PATCHES);
}

extern "C" void kernel_launch(void* const* d_in, const int* in_sizes, int n_in,
                              void* d_out, int out_size, void* d_ws, size_t ws_size,
                              hipStream_t stream) {
    const float* x = (const float*)d_in[0];
    float* out = (float*)d_out;
    int* ws = (int*)d_ws;

    const int nimg = in_sizes[0] / NPIX;  // 2048
    const int ngroups = out_size;         // 32

    hipMemsetAsync(ws, 0, ngroups * sizeof(int), stream);
    cc_kernel<<<nimg, 256, 0, stream>>>(x, ws);
    finalize_kernel<<<1, 64, 0, stream>>>(ws, out, ngroups);
}

// Round 6
// 21.341 us; speedup vs baseline: 2.1461x; 1.7696x over previous
//
#include <hip/hip_runtime.h>

// x: [2,2,8,64,64,64] fp32 0/1 -> 2048 images of 64x64.
// Per image: #4-connected components; per group of 64 images: sum // 64 -> float.
//
// One 256-thread block per image; thread = 4*row + quarter. Each thread loads
// 16 consecutive pixels (one 64B line), builds a 16-bit quarter mask; 2x
// shfl_xor(width=4) assemble full row masks. Horizontal runs are free
// (bitmask). Union-find over runs (id = row*32+rank) in an 8 KB LDS table
// using atomicMin HOOKING (no CAS retry convoys): each contended union
// resolves in the LDS atomic pipe instead of a software retry + re-find.
// components = total_runs - root_kills; per-image count -> plain store,
// reduced by a tiny second kernel (no memset, no global atomics).
constexpr int NPIX = 64 * 64;
constexpr int PATCHES = 64;
constexpr int RUNS_PER_ROW = 32;
constexpr int TABLE = 64 * RUNS_PER_ROW;  // 2048 run slots

// Find with path halving. All values ever written to p[i] are < i, so walks
// strictly decrease and terminate; halving stores only ever redirect a
// non-root to another in-component node (merge loop repairs any severed
// link via its continuation), so races are benign.
__device__ __forceinline__ int find_root(volatile int* p, int i) {
    while (true) {
        int pi = p[i];
        if (pi == i) return i;
        int gp = p[pi];
        if (gp == pi) return pi;
        p[i] = gp;
        i = gp;
    }
}

// Priority union via atomicMin. Returns 1 iff this call killed a root
// (p[b] transitioned b -> smaller exactly once, seen by a unique thread).
__device__ __forceinline__ int merge(int* p, int a, int b) {
    while (true) {
        a = find_root(p, a);
        b = find_root(p, b);
        if (a == b) return 0;
        if (a > b) { int t = a; a = b; b = t; }  // a < b
        int old = atomicMin(&p[b], a);
        if (old == b) return 1;  // we killed root b
        b = old;                 // p[b] was already smaller; chase it
    }
}

__global__ __launch_bounds__(256, 8) void cc_kernel(const float* __restrict__ in,
                                                    int* __restrict__ counts) {
    __shared__ int par[TABLE];               // 8 KB
    __shared__ unsigned long long mrow[64];  // row masks
    __shared__ int wpart[4];
    const int tid = threadIdx.x;
    const int img = blockIdx.x;
    const int r = tid >> 2;  // row 0..63
    const int q = tid & 3;   // quarter 0..3

    // ---- load 16 consecutive pixels (4 x float4 = one 64B line) ----
    const float4* src =
        reinterpret_cast<const float4*>(in + (size_t)img * NPIX + r * 64 + q * 16);
    float4 buf[4];
#pragma unroll
    for (int k = 0; k < 4; ++k) buf[k] = src[k];

    // ---- identity-init run table while loads are in flight ----
    {
        int b0 = tid * 4;
        *reinterpret_cast<int4*>(&par[b0]) = make_int4(b0, b0 + 1, b0 + 2, b0 + 3);
        int b1 = 1024 + tid * 4;
        *reinterpret_cast<int4*>(&par[b1]) = make_int4(b1, b1 + 1, b1 + 2, b1 + 3);
    }

    // ---- 16-bit quarter mask, then full row mask via width-4 butterfly ----
    unsigned qm = 0;
#pragma unroll
    for (int k = 0; k < 4; ++k) {
        qm |= (buf[k].x > 0.5f ? 1u : 0u) << (4 * k);
        qm |= (buf[k].y > 0.5f ? 2u : 0u) << (4 * k);
        qm |= (buf[k].z > 0.5f ? 4u : 0u) << (4 * k);
        qm |= (buf[k].w > 0.5f ? 8u : 0u) << (4 * k);
    }
    unsigned long long m = (unsigned long long)qm << (16 * q);
    m |= __shfl_xor(m, 1, 4);
    m |= __shfl_xor(m, 2, 4);  // all 4 threads of row r hold the full mask

    if (q == 0) mrow[r] = m;
    __syncthreads();  // par + mrow visible

    const unsigned long long ma = m;
    const unsigned long long mb = (r < 63) ? mrow[r + 1] : 0ull;
    const unsigned long long sa = ma & ~(ma << 1);
    const unsigned long long sb = mb & ~(mb << 1);
    const unsigned long long qmask = 0xFFFFull << (16 * q);

    int cnt = __popcll(sa & qmask);  // run starts partitioned by quarter

    // ---- unions: overlap segments whose start bit is in this quarter ----
    unsigned long long both = ma & mb;
    unsigned long long ov = (both & ~(both << 1)) & qmask;
    while (ov) {
        int x = __builtin_ctzll(ov);
        ov &= ov - 1;
        unsigned long long below = (2ull << x) - 1;  // bits 0..x
        int ida = r * RUNS_PER_ROW + __popcll(sa & below) - 1;
        int idb = (r + 1) * RUNS_PER_ROW + __popcll(sb & below) - 1;
        cnt -= merge(par, ida, idb);
    }

    // ---- block reduction of (runs - kills); plain store, no atomics ----
#pragma unroll
    for (int d = 32; d > 0; d >>= 1) cnt += __shfl_xor(cnt, d, 64);
    if ((tid & 63) == 0) wpart[tid >> 6] = cnt;
    __syncthreads();
    if (tid == 0) counts[img] = wpart[0] + wpart[1] + wpart[2] + wpart[3];
}

// One block: group g = 8 threads summing its 64 per-image counts.
__global__ void finalize_kernel(const int* __restrict__ counts,
                                float* __restrict__ out, int ngroups) {
    const int t = threadIdx.x;
    const int g = t >> 3, j = t & 7;
    if (g >= ngroups) return;
    const int* c = counts + g * PATCHES + j * 8;
    int s = 0;
#pragma unroll
    for (int k = 0; k < 8; ++k) s += c[k];
#pragma unroll
    for (int d = 4; d > 0; d >>= 1) s += __shfl_down(s, d, 8);
    if (j == 0) out[g] = (float)(s >> 6);  // sum // 64 (sum >= 0)
}

extern "C" void kernel_launch(void* const* d_in, const int* in_sizes, int n_in,
                              void* d_out, int out_size, void* d_ws, size_t ws_size,
                              hipStream_t stream) {
    const float* x = (const float*)d_in[0];
    float* out = (float*)d_out;
    int* counts = (int*)d_ws;

    const int nimg = in_sizes[0] / NPIX;  // 2048
    const int ngroups = out_size;         // 32

    cc_kernel<<<nimg, 256, 0, stream>>>(x, counts);
    finalize_kernel<<<1, ngroups * 8, 0, stream>>>(counts, out, ngroups);
}